// Round 10
// baseline (359.882 us; speedup 1.0000x reference)
//
#include <hip/hip_runtime.h>
#include <hip/hip_bf16.h>

typedef unsigned int  u32;
typedef unsigned short u16;
typedef __attribute__((ext_vector_type(8))) short bf16x8;
typedef __attribute__((ext_vector_type(4))) float f32x4;
typedef __attribute__((ext_vector_type(4))) u32 u32x4;

#define NPIX 65536

// ---------------- ws byte offsets ----------------
constexpr size_t SIG   = 0;
constexpr size_t B1OFF = 256;
constexpr size_t B2OFF = B1OFF + 2048;
constexpr size_t WC1   = B2OFF + 1024;        // conv1 W frag-stream (128x576)
constexpr size_t WC2   = WC1 + 147456;        // conv2 (64x1152)
constexpr size_t WF1   = WC2 + 147456;        // conv3 (128x1152)
constexpr size_t WF2   = WF1 + 294912;        // conv4 (64x1152)
constexpr size_t WP1   = WF2 + 147456;        // 512x64
constexpr size_t WP2   = WP1 + 65536;         // 256x128
constexpr size_t XB    = WP2 + 65536;         // 65536x64 bf16
constexpr size_t HBUF  = XB + 8388608;        // 65536x128 bf16
constexpr size_t QKVS2 = HBUF + 16777216;     // 65536x256 bf16
constexpr size_t XC    = QKVS2 + 33554432;    // 65536x128 bf16 concat
constexpr size_t QKVS1 = XC + 16777216;       // 65536x512 bf16
constexpr size_t Y1    = QKVS1;
constexpr size_t TBUF  = QKVS1 + 16777216;
constexpr size_t GRAM  = QKVS1 + 67108864;

// ---------------- helpers ----------------
__device__ __forceinline__ float gelu_f(float v) {
    float xa = fabsf(v) * 0.70710678118654752f;
    float t  = __fdividef(1.0f, fmaf(0.3275911f, xa, 1.0f));
    float poly = t * fmaf(t, fmaf(t, fmaf(t, fmaf(t, 1.061405429f, -1.453152027f),
                   1.421413741f), -0.284496736f), 0.254829592f);
    float erfv = 1.0f - poly * __expf(-xa * xa);
    erfv = copysignf(erfv, v);
    return 0.5f * v * (1.0f + erfv);
}
__device__ __forceinline__ u16 f2bf(float f) {
    __hip_bfloat16 b = __float2bfloat16(f);
    return *reinterpret_cast<u16*>(&b);
}
__device__ __forceinline__ float blo(u32 u) {
    union { u32 i; float f; } x; x.i = u << 16; return x.f;
}
__device__ __forceinline__ float bhi(u32 u) {
    union { u32 i; float f; } x; x.i = u & 0xffff0000u; return x.f;
}
__device__ __forceinline__ u32 packbf(float a, float b) {
    return (u32)f2bf(a) | ((u32)f2bf(b) << 16);
}
__device__ __forceinline__ void g2l16(const void* g, void* l) {
    __builtin_amdgcn_global_load_lds(
        (const __attribute__((address_space(1))) u32*)g,
        (__attribute__((address_space(3))) u32*)l, 16, 0, 0);
}
template<int N>
__device__ __forceinline__ void waitvm() {
    asm volatile("s_waitcnt vmcnt(%0)" :: "n"(N) : "memory");
}

// ---------------- block reduction ----------------
__device__ float block_sum(float vv, float* red) {
    #pragma unroll
    for (int m = 1; m < 64; m <<= 1) vv += __shfl_xor(vv, m);
    int tid = threadIdx.x;
    __syncthreads();
    if ((tid & 63) == 0) red[tid >> 6] = vv;
    __syncthreads();
    return red[0] + red[1] + red[2] + red[3];
}

// ---------------- Gram matrix ----------------
__global__ __launch_bounds__(256)
void gram_kernel(const float* __restrict__ cW1, const float* __restrict__ cW2,
                 const float* __restrict__ fW1, const float* __restrict__ fW2,
                 float* __restrict__ Gall) {
    int bid = blockIdx.x;
    const float* W; int O, K, wsel, tile;
    if (bid < 64)       { W = cW1; O = 128; K = 576;  wsel = 0; tile = bid; }
    else if (bid < 80)  { W = cW2; O = 64;  K = 1152; wsel = 1; tile = bid - 64; }
    else if (bid < 144) { W = fW1; O = 128; K = 1152; wsel = 2; tile = bid - 80; }
    else                { W = fW2; O = 64;  K = 1152; wsel = 3; tile = bid - 144; }
    int ntiles = O >> 4;
    int ti0 = (tile / ntiles) << 4, tj0 = (tile % ntiles) << 4;
    __shared__ float Wi[16][33], Wj[16][33];
    int tid = threadIdx.x;
    int ti = tid >> 4, tj = tid & 15;
    int r = tid >> 5, c = tid & 31;
    float acc = 0.f;
    for (int k0 = 0; k0 < K; k0 += 32) {
        Wi[r][c]     = W[(size_t)(ti0 + r) * K + k0 + c];
        Wi[r + 8][c] = W[(size_t)(ti0 + r + 8) * K + k0 + c];
        Wj[r][c]     = W[(size_t)(tj0 + r) * K + k0 + c];
        Wj[r + 8][c] = W[(size_t)(tj0 + r + 8) * K + k0 + c];
        __syncthreads();
        #pragma unroll
        for (int k = 0; k < 32; ++k)
            acc += Wi[ti][k] * Wj[tj][k];
        __syncthreads();
    }
    Gall[wsel * 16384 + (ti0 + ti) * 128 + (tj0 + tj)] = acc;
}

// ---------------- power iteration ----------------
__global__ __launch_bounds__(256)
void power_kernel(const float* __restrict__ Gall, float* __restrict__ sig) {
    int wsel = blockIdx.x;
    const float* G = Gall + wsel * 16384;
    const int O = (wsel == 0 || wsel == 2) ? 128 : 64;
    __shared__ float u[128], t[128], red[4];
    int tid = threadIdx.x;
    if (tid < O) u[tid] = 1.0f / sqrtf((float)O);
    __syncthreads();
    for (int it = 0; it < 3; ++it) {
        if (tid < O) {
            float s = 0.f;
            const float4* gr = reinterpret_cast<const float4*>(G + (size_t)tid * 128);
            for (int j = 0; j < O / 4; ++j) {
                float4 g = gr[j];
                s += g.x * u[4*j] + g.y * u[4*j+1] + g.z * u[4*j+2] + g.w * u[4*j+3];
            }
            t[tid] = s;
        }
        __syncthreads();
        float loc = (tid < O) ? t[tid] * t[tid] : 0.f;
        float nt = sqrtf(block_sum(loc, red));
        if (it == 2) {
            float locd = (tid < O) ? u[tid] * t[tid] : 0.f;
            float dot = block_sum(locd, red);
            if (tid == 0) sig[wsel] = nt / sqrtf(dot + 1e-24f);
        } else {
            if (tid < O) u[tid] = t[tid] / (nt + 1e-12f);
            __syncthreads();
        }
    }
}

// ---------------- conv weight prep: frag-stream layout ----------------
// dst[nh][kt][s][nf][lane][8]: lane = ((k%32)/8)*16 + (o%16within nf),
// so each wave B-fragment is one coalesced 1KB global_load_dwordx4.
__global__ __launch_bounds__(256)
void prep_conv_w(const float* __restrict__ cW1, const float* __restrict__ cW2,
                 const float* __restrict__ fW1, const float* __restrict__ fW2,
                 const float* __restrict__ sig,
                 u16* wc1, u16* wc2, u16* wf1, u16* wf2) {
    int wsel = blockIdx.y;
    const float* src; u16* dst; int O, C;
    switch (wsel) {
        case 0:  src = cW1; dst = wc1; O = 128; C = 64;  break;
        case 1:  src = cW2; dst = wc2; O = 64;  C = 128; break;
        case 2:  src = fW1; dst = wf1; O = 128; C = 128; break;
        default: src = fW2; dst = wf2; O = 64;  C = 128; break;
    }
    const int NSTEP = (C * 9) / 64;
    int idx = blockIdx.x * 256 + threadIdx.x;
    if (idx >= O * C * 9) return;
    int o = idx / (C * 9);
    int rem = idx - o * (C * 9);
    int ci = rem / 9, tap = rem - ci * 9;
    int k = tap * C + ci;
    int nh = o >> 6, n6 = o & 63;
    int nf = n6 >> 4, lr = n6 & 15;
    int kt = k >> 6, r = k & 63;
    int s = r >> 5, lg = (r & 31) >> 3, e = r & 7;
    int lane = lg * 16 + lr;
    float v = src[idx] / sig[wsel];
    dst[((((size_t)(nh * NSTEP + kt) * 2 + s) * 4 + nf) * 64 + lane) * 8 + e] = f2bf(v);
}

// ---------------- projection weight/bias prep ----------------
__global__ __launch_bounds__(256)
void prep_proj(const float* q1W, const float* k1W, const float* v1W, const float* s1W,
               const float* q2W, const float* k2W, const float* v2W, const float* s2W,
               const float* q1b, const float* k1b, const float* v1b, const float* s1b,
               const float* q2b, const float* k2b, const float* v2b, const float* s2b,
               u16* wp1, u16* wp2, float* b1, float* b2) {
    const float* W1[4] = {q1W, k1W, v1W, s1W};
    const float* W2[4] = {q2W, k2W, v2W, s2W};
    const float* Bb1[4] = {q1b, k1b, v1b, s1b};
    const float* Bb2[4] = {q2b, k2b, v2b, s2b};
    int idx = blockIdx.x * 256 + threadIdx.x;
    if (idx < 32768) {
        int w = idx >> 13, r = idx & 8191;
        wp1[(size_t)w * 8192 + r] = f2bf(W1[w][r]);
    } else if (idx < 65536) {
        int j = idx - 32768; int w = j >> 13, r = j & 8191;
        wp2[(size_t)w * 8192 + r] = f2bf(W2[w][r]);
    } else if (idx < 66048) {
        int j = idx - 65536; int w = j >> 7; b1[j] = Bb1[w][j & 127];
    } else if (idx < 66304) {
        int j = idx - 66048; int w = j >> 6; b2[j] = Bb2[w][j & 63];
    }
}

// ---------------- x NCHW f32 -> [pix][64] bf16 ----------------
__global__ __launch_bounds__(256)
void convert_x(const float* __restrict__ x, u16* __restrict__ xb) {
    __shared__ float tile[64][65];
    int b = blockIdx.x >> 6, y = blockIdx.x & 63;
    int tid = threadIdx.x;
    #pragma unroll
    for (int i = 0; i < 16; ++i) {
        int c = (tid >> 6) + i * 4;
        tile[c][tid & 63] = x[(((size_t)b * 64 + c) << 12) + (y << 6) + (tid & 63)];
    }
    __syncthreads();
    #pragma unroll
    for (int i = 0; i < 16; ++i) {
        int idx = tid + i * 256;
        int p = idx >> 6, c = idx & 63;
        xb[(((size_t)b << 12) + (y << 6) + p) * 64 + c] = f2bf(tile[c][p]);
    }
}

// ---------------- barrier-free direct conv ----------------
// Block = 4 image rows x 64 cols, 4 waves = 1 full row each (mf=4 -> max
// B-frag reuse). A halo (6 x W x CC) staged ONCE (one vmcnt(0)+barrier);
// then the entire K x nh loop runs with ZERO barriers: A frags from LDS,
// B frags direct-from-global in frag-stream layout (1KB coalesced loads,
// L2-resident panel), register double-buffered one step ahead. Fully
// unrolled so all tap offsets are immediates and the compiler inserts
// counted waits itself.
template<int CC, int NH, int OUTM>
__global__ __launch_bounds__(256)
void conv_kernel(const u16* __restrict__ A, const u16* __restrict__ Bf,
                 const float* __restrict__ bias, void* __restrict__ Cout,
                 int ostride, int ocol0, int do_gelu) {
    constexpr int NSTEP = (CC * 9) / 64;   // 9 (CC=64) or 18 (CC=128)
    constexpr int NCH8 = CC / 8;
    constexpr int CPL = 512 / CC;          // cols per 1KB wave-load
    constexpr int NLR = (66 + CPL - 1) / CPL;
    constexpr int W = NLR * CPL;           // 72 (CC=64) / 68 (CC=128)
    __shared__ u16 Als[6 * W * CC];

    const int tid = threadIdx.x;
    const int w = tid >> 6;
    const int lane = tid & 63;
    const int img = blockIdx.x >> 4;
    const int y0 = (blockIdx.x & 15) << 2;

    // ---- stage A halo once (clamped, inverse-swizzled source) ----
    {
        const int TL = 6 * NLR;
        const int cch = lane & (NCH8 - 1);
        const int cof = lane / NCH8;
        for (int L = w; L < TL; L += 4) {
            int row = L / NLR, cb = (L - row * NLR) * CPL;
            int c = cb + cof;
            int yy = min(max(y0 + row - 1, 0), 63);
            int xx = min(max(c - 1, 0), 63);
            const u16* g = A + (size_t)((img << 12) + (yy << 6) + xx) * CC
                             + ((cch ^ (c & (NCH8 - 1))) << 3);
            g2l16(g, &Als[(row * W + cb) * CC]);
        }
    }
    waitvm<0>();
    __builtin_amdgcn_s_barrier();
    // ------------- no barriers from here on -------------

    const int yw = y0 + w;
    const int lr = lane & 15, lg = lane >> 4;

    for (int nh = 0; nh < NH; ++nh) {
        f32x4 acc[4][4];
        #pragma unroll
        for (int i = 0; i < 4; ++i)
            #pragma unroll
            for (int j = 0; j < 4; ++j) {
                f32x4 z = {0.f, 0.f, 0.f, 0.f};
                acc[i][j] = z;
            }

        const u16* Bn = Bf + ((size_t)(nh * NSTEP) << 12) + (lane << 3);
        auto loadB = [&](bf16x8 (&dst)[8], int kt) {
            const u16* p = Bn + ((size_t)kt << 12);
            #pragma unroll
            for (int i = 0; i < 8; ++i)
                dst[i] = *reinterpret_cast<const bf16x8*>(p + ((size_t)i << 9));
        };

        bf16x8 bfr[2][8];
        loadB(bfr[0], 0);

        #pragma unroll
        for (int kt = 0; kt < NSTEP; ++kt) {
            constexpr int dummy = 0; (void)dummy;
            const int cur = kt & 1;
            if (kt + 1 < NSTEP) loadB(bfr[cur ? 0 : 1], kt + 1);
            const int tap = (CC == 128) ? (kt >> 1) : kt;
            const int t3 = (tap * 11) >> 5;
            const int dy = t3 - 1, dx = tap - t3 * 3 - 1;
            const int rowbase = (w + dy + 1) * (W * CC);
            #pragma unroll
            for (int s = 0; s < 2; ++s) {
                const int k8 = ((CC == 128) ? ((kt & 1) << 3) : 0) + (s << 2) + lg;
                bf16x8 af[4];
                #pragma unroll
                for (int mf = 0; mf < 4; ++mf) {
                    int col_l = mf * 16 + lr + dx + 1;
                    int addr = rowbase + col_l * CC
                             + ((k8 ^ (col_l & (NCH8 - 1))) << 3);
                    af[mf] = *reinterpret_cast<const bf16x8*>(&Als[addr]);
                }
                #pragma unroll
                for (int nf = 0; nf < 4; ++nf) {
                    bf16x8 bv = cur ? bfr[1][s * 4 + nf] : bfr[0][s * 4 + nf];
                    #pragma unroll
                    for (int mf = 0; mf < 4; ++mf)
                        acc[mf][nf] = __builtin_amdgcn_mfma_f32_16x16x32_bf16(
                            af[mf], bv, acc[mf][nf], 0, 0, 0);
                }
            }
        }

        // epilogue for this 64-channel half
        #pragma unroll
        for (int mf = 0; mf < 4; ++mf) {
            int xbase = mf * 16 + lg * 4;
            #pragma unroll
            for (int nf = 0; nf < 4; ++nf) {
                int ch = (nh << 6) + nf * 16 + lr;
                float bv = bias[ch];
                if (OUTM == 0) {
                    u16* Co = (u16*)Cout;
                    #pragma unroll
                    for (int j = 0; j < 4; ++j) {
                        float v = acc[mf][nf][j] + bv;
                        if (do_gelu) v = gelu_f(v);
                        int n = (img << 12) + (yw << 6) + xbase + j;
                        Co[(size_t)n * ostride + ocol0 + ch] = f2bf(v);
                    }
                } else {
                    float* Co = (float*)Cout;
                    f32x4 vv;
                    #pragma unroll
                    for (int j = 0; j < 4; ++j)
                        vv[j] = gelu_f(acc[mf][nf][j] + bv);
                    *reinterpret_cast<f32x4*>(
                        &Co[((size_t)((img << 6) + ch) << 12) + (yw << 6) + xbase]) = vv;
                }
            }
        }
    }
}

// ---------------- projection GEMM (BK=64, ring-3) ----------------
template<int TAPS, int CC, int BN, int OUTM>
__global__ __launch_bounds__(256)
void mm_kernel(const u16* __restrict__ A, const u16* __restrict__ Bw,
               const float* __restrict__ bias, void* __restrict__ Cout,
               int ostride, int ocol0, int do_gelu) {
    constexpr int K = CC * TAPS;
    constexpr int NSTEP = K / 64;
    constexpr int NF = BN / 32;
    constexpr int HN = BN / 2;
    constexpr int LPS = 2 + BN / 32;
    __shared__ u16 Als[3][64 * 64];
    __shared__ u16 Bls[3][BN * 64];
    const int tid = threadIdx.x;
    const int w = tid >> 6;
    const int lane = tid & 63;
    const int m0 = blockIdx.x * 64;
    const int nt0 = blockIdx.y * BN;
    const int wm = w >> 1, wn = w & 1;
    const int cg8 = (((tid & 7) ^ ((tid >> 3) & 7)) << 3);

    const int r0 = (w << 3) + ((tid >> 3) & 7);
    const int mA0 = m0 + r0;
    const int mA1 = mA0 + 32;
    const u16* Bbase = Bw + (size_t)(nt0 + r0) * K + cg8;

    int offA[2][2], offB[2][NF];
    #pragma unroll
    for (int s = 0; s < 2; ++s) {
        #pragma unroll
        for (int mf = 0; mf < 2; ++mf) {
            int R = wm * 32 + mf * 16 + (lane & 15);
            int cl = s * 4 + (lane >> 4);
            offA[s][mf] = R * 64 + ((cl ^ (R & 7)) << 3);
        }
        #pragma unroll
        for (int nf = 0; nf < NF; ++nf) {
            int Rb = wn * HN + nf * 16 + (lane & 15);
            int cl = s * 4 + (lane >> 4);
            offB[s][nf] = Rb * 64 + ((cl ^ (Rb & 7)) << 3);
        }
    }

    f32x4 acc[2][NF];
    #pragma unroll
    for (int i = 0; i < 2; ++i)
        #pragma unroll
        for (int j = 0; j < NF; ++j) {
            f32x4 z = {0.f, 0.f, 0.f, 0.f};
            acc[i][j] = z;
        }

    auto stage = [&](int s) {
        const int buf = s % 3;
        const int kk = s * 64;
        g2l16(A + (size_t)mA0 * CC + kk + cg8, &Als[buf][(w << 3) * 64]);
        g2l16(A + (size_t)mA1 * CC + kk + cg8, &Als[buf][(32 + (w << 3)) * 64]);
        #pragma unroll
        for (int i = 0; i < BN / 32; ++i)
            g2l16(Bbase + (size_t)i * 32 * K + kk, &Bls[buf][(i * 32 + (w << 3)) * 64]);
    };

    stage(0);
    if constexpr (NSTEP > 1) stage(1);

    for (int kt = 0; kt < NSTEP; ++kt) {
        if (kt < NSTEP - 1) waitvm<LPS>(); else waitvm<0>();
        __builtin_amdgcn_s_barrier();
        __builtin_amdgcn_sched_barrier(0);
        if (kt + 2 < NSTEP) stage(kt + 2);
        __builtin_amdgcn_sched_barrier(0);
        const u16* Ab = &Als[kt % 3][0];
        const u16* Bb = &Bls[kt % 3][0];
        #pragma unroll
        for (int s = 0; s < 2; ++s) {
            bf16x8 af[2];
            #pragma unroll
            for (int mf = 0; mf < 2; ++mf)
                af[mf] = *reinterpret_cast<const bf16x8*>(Ab + offA[s][mf]);
            #pragma unroll
            for (int nf = 0; nf < NF; ++nf) {
                bf16x8 bfv = *reinterpret_cast<const bf16x8*>(Bb + offB[s][nf]);
                #pragma unroll
                for (int mf = 0; mf < 2; ++mf)
                    acc[mf][nf] = __builtin_amdgcn_mfma_f32_16x16x32_bf16(
                        af[mf], bfv, acc[mf][nf], 0, 0, 0);
            }
        }
    }

    #pragma unroll
    for (int mf = 0; mf < 2; ++mf) {
        int mrow = m0 + wm * 32 + mf * 16 + (lane >> 4) * 4;
        #pragma unroll
        for (int nf = 0; nf < NF; ++nf) {
            int col = nt0 + wn * HN + nf * 16 + (lane & 15);
            float bv = bias[col];
            u16* Co = (u16*)Cout;
            #pragma unroll
            for (int j = 0; j < 4; ++j) {
                float v = acc[mf][nf][j] + bv;
                if (do_gelu) v = gelu_f(v);
                Co[(size_t)(mrow + j) * ostride + ocol0 + col] = f2bf(v);
            }
        }
    }
}

// ---------------- attention layer 1: heads=8, d=16, 8ch/lane ----------------
__global__ __launch_bounds__(256)
void attn1_kernel(const u16* __restrict__ qkvs, u16* __restrict__ h) {
    const int tid = threadIdx.x;
    const int l16 = tid & 15;
    const int n = blockIdx.x * 16 + (tid >> 4);
    const int y = (n >> 6) & 63, x = n & 63;
    const u32* qk = (const u32*)qkvs;
    const int nbase = (n << 8) + l16 * 4;

    u32x4 qp = *(const u32x4*)(qk + nbase);
    float q[8];
    #pragma unroll
    for (int i = 0; i < 4; ++i) { q[2*i] = blo(qp[i]); q[2*i+1] = bhi(qp[i]); }

    float al[9];
    float mx = -1e30f;
    #pragma unroll
    for (int e = 0; e < 9; ++e) {
        const int dy = e / 3 - 1, dx = e % 3 - 1;
        const bool valid = (unsigned)(y + dy) < 64u && (unsigned)(x + dx) < 64u;
        const int off = valid ? ((dy * 64 + dx) << 8) : 0;
        u32x4 kp = *(const u32x4*)(qk + nbase + off + 64);
        float p = 0.f;
        #pragma unroll
        for (int i = 0; i < 4; ++i) {
            p = fmaf(q[2*i],   blo(kp[i]), p);
            p = fmaf(q[2*i+1], bhi(kp[i]), p);
        }
        p += __shfl_xor(p, 1);
        al[e] = valid ? p * 0.25f : -1e30f;
        mx = fmaxf(mx, al[e]);
    }
    float s = 0.f;
    #pragma unroll
    for (int e = 0; e < 9; ++e) { al[e] = __expf(al[e] - mx); s += al[e]; }

    float o[8] = {0.f, 0.f, 0.f, 0.f, 0.f, 0.f, 0.f, 0.f};
    #pragma unroll
    for (int e = 0; e < 9; ++e) {
        const int dy = e / 3 - 1, dx = e % 3 - 1;
        const bool valid = (unsigned)(y + dy) < 64u && (unsigned)(x + dx) < 64u;
        const int off = valid ? ((dy * 64 + dx) << 8) : 0;
        u32x4 vp = *(const u32x4*)(qk + nbase + off + 128);
        const float a = al[e];
        #pragma unroll
        for (int i = 0; i < 4; ++i) {
            o[2*i]   = fmaf(a, blo(vp[i]), o[2*i]);
            o[2*i+1] = fmaf(a, bhi(vp[i]), o[2*i+1]);
        }
    }
    const float r = __fdividef(1.0f, s + 1e-16f);
    u32x4 sp = *(const u32x4*)(qk + nbase + 192);
    u32x4 res;
    #pragma unroll
    for (int i = 0; i < 4; ++i) {
        float h0 = gelu_f(fmaf(o[2*i],   r, blo(sp[i])));
        float h1 = gelu_f(fmaf(o[2*i+1], r, bhi(sp[i])));
        res[i] = packbf(h0, h1);
    }
    *(u32x4*)((u32*)h + (n << 6) + l16 * 4) = res;
}

// ---------------- attention layer 2: heads=1, d=64, 8ch/lane ----------------
__global__ __launch_bounds__(256)
void attn2_kernel(const u16* __restrict__ qkvs, u16* __restrict__ xc) {
    const int tid = threadIdx.x;
    const int l8 = tid & 7;
    const int n = blockIdx.x * 32 + (tid >> 3);
    const int y = (n >> 6) & 63, x = n & 63;
    const u32* qk = (const u32*)qkvs;
    const int nbase = (n << 7) + l8 * 4;

    u32x4 qp = *(const u32x4*)(qk + nbase);
    float q[8];
    #pragma unroll
    for (int i = 0; i < 4; ++i) { q[2*i] = blo(qp[i]); q[2*i+1] = bhi(qp[i]); }

    float al[9];
    float mx = -1e30f;
    #pragma unroll
    for (int e = 0; e < 9; ++e) {
        const int dy = e / 3 - 1, dx = e % 3 - 1;
        const bool valid = (unsigned)(y + dy) < 64u && (unsigned)(x + dx) < 64u;
        const int off = valid ? ((dy * 64 + dx) << 7) : 0;
        u32x4 kp = *(const u32x4*)(qk + nbase + off + 32);
        float p = 0.f;
        #pragma unroll
        for (int i = 0; i < 4; ++i) {
            p = fmaf(q[2*i],   blo(kp[i]), p);
            p = fmaf(q[2*i+1], bhi(kp[i]), p);
        }
        p += __shfl_xor(p, 1);
        p += __shfl_xor(p, 2);
        p += __shfl_xor(p, 4);
        al[e] = valid ? p * 0.125f : -1e30f;
        mx = fmaxf(mx, al[e]);
    }
    float s = 0.f;
    #pragma unroll
    for (int e = 0; e < 9; ++e) { al[e] = __expf(al[e] - mx); s += al[e]; }

    float o[8] = {0.f, 0.f, 0.f, 0.f, 0.f, 0.f, 0.f, 0.f};
    #pragma unroll
    for (int e = 0; e < 9; ++e) {
        const int dy = e / 3 - 1, dx = e % 3 - 1;
        const bool valid = (unsigned)(y + dy) < 64u && (unsigned)(x + dx) < 64u;
        const int off = valid ? ((dy * 64 + dx) << 7) : 0;
        u32x4 vp = *(const u32x4*)(qk + nbase + off + 64);
        const float a = al[e];
        #pragma unroll
        for (int i = 0; i < 4; ++i) {
            o[2*i]   = fmaf(a, blo(vp[i]), o[2*i]);
            o[2*i+1] = fmaf(a, bhi(vp[i]), o[2*i+1]);
        }
    }
    const float r = __fdividef(1.0f, s + 1e-16f);
    u32x4 sp = *(const u32x4*)(qk + nbase + 96);
    u32x4 res;
    #pragma unroll
    for (int i = 0; i < 4; ++i) {
        float h0 = gelu_f(fmaf(o[2*i],   r, blo(sp[i])));
        float h1 = gelu_f(fmaf(o[2*i+1], r, bhi(sp[i])));
        res[i] = packbf(h0, h1);
    }
    *(u32x4*)((u32*)xc + (n << 6) + 32 + l8 * 4) = res;
}

// ---------------- host launcher ----------------
extern "C" void kernel_launch(void* const* d_in, const int* in_sizes, int n_in,
                              void* d_out, int out_size, void* d_ws, size_t ws_size,
                              hipStream_t stream) {
    const float* x   = (const float*)d_in[0];
    const float* cW1 = (const float*)d_in[1];
    const float* cb1 = (const float*)d_in[2];
    const float* cW2 = (const float*)d_in[3];
    const float* cb2 = (const float*)d_in[4];
    const float* q1W = (const float*)d_in[5];
    const float* q1b = (const float*)d_in[6];
    const float* k1W = (const float*)d_in[7];
    const float* k1b = (const float*)d_in[8];
    const float* v1W = (const float*)d_in[9];
    const float* v1b = (const float*)d_in[10];
    const float* s1W = (const float*)d_in[11];
    const float* s1b = (const float*)d_in[12];
    const float* q2W = (const float*)d_in[13];
    const float* q2b = (const float*)d_in[14];
    const float* k2W = (const float*)d_in[15];
    const float* k2b = (const float*)d_in[16];
    const float* v2W = (const float*)d_in[17];
    const float* v2b = (const float*)d_in[18];
    const float* s2W = (const float*)d_in[19];
    const float* s2b = (const float*)d_in[20];
    const float* fW1 = (const float*)d_in[21];
    const float* fb1 = (const float*)d_in[22];
    const float* fW2 = (const float*)d_in[23];
    const float* fb2 = (const float*)d_in[24];

    char* ws = (char*)d_ws;
    float* sig  = (float*)(ws + SIG);
    float* b1   = (float*)(ws + B1OFF);
    float* b2   = (float*)(ws + B2OFF);
    u16* wc1    = (u16*)(ws + WC1);
    u16* wc2    = (u16*)(ws + WC2);
    u16* wf1    = (u16*)(ws + WF1);
    u16* wf2    = (u16*)(ws + WF2);
    u16* wp1    = (u16*)(ws + WP1);
    u16* wp2    = (u16*)(ws + WP2);
    u16* xb     = (u16*)(ws + XB);
    u16* hbuf   = (u16*)(ws + HBUF);
    u16* qkvs2  = (u16*)(ws + QKVS2);
    u16* xc     = (u16*)(ws + XC);
    u16* qkvs1  = (u16*)(ws + QKVS1);
    u16* y1     = (u16*)(ws + Y1);
    u16* tbuf   = (u16*)(ws + TBUF);
    float* gram = (float*)(ws + GRAM);
    float* out  = (float*)d_out;

    gram_kernel<<<160, 256, 0, stream>>>(cW1, cW2, fW1, fW2, gram);
    power_kernel<<<4, 256, 0, stream>>>(gram, sig);
    prep_conv_w<<<dim3(576, 4), 256, 0, stream>>>(cW1, cW2, fW1, fW2, sig,
                                                  wc1, wc2, wf1, wf2);
    prep_proj<<<260, 256, 0, stream>>>(q1W, k1W, v1W, s1W, q2W, k2W, v2W, s2W,
                                       q1b, k1b, v1b, s1b, q2b, k2b, v2b, s2b,
                                       wp1, wp2, b1, b2);
    convert_x<<<1024, 256, 0, stream>>>(x, xb);

    // proj1: [N][64] x [512][64]^T -> qkvs1 [N][512]
    mm_kernel<1, 64, 128, 0><<<dim3(1024, 4), 256, 0, stream>>>(
        xb, wp1, b1, qkvs1, 512, 0, 0);
    attn1_kernel<<<NPIX / 16, 256, 0, stream>>>(qkvs1, hbuf);
    // proj2: [N][128] x [256][128]^T -> qkvs2 [N][256]
    mm_kernel<1, 128, 128, 0><<<dim3(1024, 2), 256, 0, stream>>>(
        hbuf, wp2, b2, qkvs2, 256, 0, 0);
    attn2_kernel<<<NPIX / 32, 256, 0, stream>>>(qkvs2, xc);

    // conv1: xb (C=64) -> y1 [N][128], gelu
    conv_kernel<64, 2, 0><<<256, 256, 0, stream>>>(xb, wc1, cb1, y1, 128, 0, 1);
    // conv2: y1 (C=128) -> xc cols 0..63, gelu
    conv_kernel<128, 1, 0><<<256, 256, 0, stream>>>(y1, wc2, cb2, xc, 128, 0, 1);
    // conv3: xc (C=128) -> tbuf [N][128], gelu
    conv_kernel<128, 2, 0><<<256, 256, 0, stream>>>(xc, wf1, fb1, tbuf, 128, 0, 1);
    // conv4: tbuf (C=128) -> out f32 NCHW, gelu
    conv_kernel<128, 1, 1><<<256, 256, 0, stream>>>(tbuf, wf2, fb2, out, 0, 0, 1);
}

// Round 11
// 232.702 us; speedup vs baseline: 1.5465x; 1.5465x over previous
//
#include <hip/hip_runtime.h>
#include <hip/hip_bf16.h>

typedef unsigned int  u32;
typedef unsigned short u16;
typedef __attribute__((ext_vector_type(8))) short bf16x8;
typedef __attribute__((ext_vector_type(4))) float f32x4;
typedef __attribute__((ext_vector_type(4))) u32 u32x4;

#define NPIX 65536

// ---------------- ws byte offsets ----------------
constexpr size_t SIG   = 0;
constexpr size_t B1OFF = 256;
constexpr size_t B2OFF = B1OFF + 2048;
constexpr size_t WC1   = B2OFF + 1024;        // 128x576 bf16
constexpr size_t WC2   = WC1 + 147456;        // 64x1152
constexpr size_t WF1   = WC2 + 147456;        // 128x1152
constexpr size_t WF2   = WF1 + 294912;        // 64x1152
constexpr size_t WP1   = WF2 + 147456;        // 512x64
constexpr size_t WP2   = WP1 + 65536;         // 256x128
constexpr size_t XB    = WP2 + 65536;         // 65536x64 bf16
constexpr size_t HBUF  = XB + 8388608;        // 65536x128 bf16
constexpr size_t QKVS2 = HBUF + 16777216;     // 65536x256 bf16
constexpr size_t XC    = QKVS2 + 33554432;    // 65536x128 bf16 concat
constexpr size_t QKVS1 = XC + 16777216;       // 65536x512 bf16
constexpr size_t Y1    = QKVS1;
constexpr size_t TBUF  = QKVS1 + 16777216;
constexpr size_t GRAM  = QKVS1 + 67108864;

// ---------------- helpers ----------------
__device__ __forceinline__ float gelu_f(float v) {
    float xa = fabsf(v) * 0.70710678118654752f;
    float t  = __fdividef(1.0f, fmaf(0.3275911f, xa, 1.0f));
    float poly = t * fmaf(t, fmaf(t, fmaf(t, fmaf(t, 1.061405429f, -1.453152027f),
                   1.421413741f), -0.284496736f), 0.254829592f);
    float erfv = 1.0f - poly * __expf(-xa * xa);
    erfv = copysignf(erfv, v);
    return 0.5f * v * (1.0f + erfv);
}
__device__ __forceinline__ u16 f2bf(float f) {
    __hip_bfloat16 b = __float2bfloat16(f);
    return *reinterpret_cast<u16*>(&b);
}
__device__ __forceinline__ float blo(u32 u) {
    union { u32 i; float f; } x; x.i = u << 16; return x.f;
}
__device__ __forceinline__ float bhi(u32 u) {
    union { u32 i; float f; } x; x.i = u & 0xffff0000u; return x.f;
}
__device__ __forceinline__ u32 packbf(float a, float b) {
    return (u32)f2bf(a) | ((u32)f2bf(b) << 16);
}
__device__ __forceinline__ void g2l16(const void* g, void* l) {
    __builtin_amdgcn_global_load_lds(
        (const __attribute__((address_space(1))) u32*)g,
        (__attribute__((address_space(3))) u32*)l, 16, 0, 0);
}
template<int N>
__device__ __forceinline__ void waitvm() {
    asm volatile("s_waitcnt vmcnt(%0)" :: "n"(N) : "memory");
}

// ---------------- block reduction ----------------
__device__ float block_sum(float vv, float* red) {
    #pragma unroll
    for (int m = 1; m < 64; m <<= 1) vv += __shfl_xor(vv, m);
    int tid = threadIdx.x;
    __syncthreads();
    if ((tid & 63) == 0) red[tid >> 6] = vv;
    __syncthreads();
    return red[0] + red[1] + red[2] + red[3];
}

// ---------------- Gram matrix ----------------
__global__ __launch_bounds__(256)
void gram_kernel(const float* __restrict__ cW1, const float* __restrict__ cW2,
                 const float* __restrict__ fW1, const float* __restrict__ fW2,
                 float* __restrict__ Gall) {
    int bid = blockIdx.x;
    const float* W; int O, K, wsel, tile;
    if (bid < 64)       { W = cW1; O = 128; K = 576;  wsel = 0; tile = bid; }
    else if (bid < 80)  { W = cW2; O = 64;  K = 1152; wsel = 1; tile = bid - 64; }
    else if (bid < 144) { W = fW1; O = 128; K = 1152; wsel = 2; tile = bid - 80; }
    else                { W = fW2; O = 64;  K = 1152; wsel = 3; tile = bid - 144; }
    int ntiles = O >> 4;
    int ti0 = (tile / ntiles) << 4, tj0 = (tile % ntiles) << 4;
    __shared__ float Wi[16][33], Wj[16][33];
    int tid = threadIdx.x;
    int ti = tid >> 4, tj = tid & 15;
    int r = tid >> 5, c = tid & 31;
    float acc = 0.f;
    for (int k0 = 0; k0 < K; k0 += 32) {
        Wi[r][c]     = W[(size_t)(ti0 + r) * K + k0 + c];
        Wi[r + 8][c] = W[(size_t)(ti0 + r + 8) * K + k0 + c];
        Wj[r][c]     = W[(size_t)(tj0 + r) * K + k0 + c];
        Wj[r + 8][c] = W[(size_t)(tj0 + r + 8) * K + k0 + c];
        __syncthreads();
        #pragma unroll
        for (int k = 0; k < 32; ++k)
            acc += Wi[ti][k] * Wj[tj][k];
        __syncthreads();
    }
    Gall[wsel * 16384 + (ti0 + ti) * 128 + (tj0 + tj)] = acc;
}

// ---------------- power iteration ----------------
__global__ __launch_bounds__(256)
void power_kernel(const float* __restrict__ Gall, float* __restrict__ sig) {
    int wsel = blockIdx.x;
    const float* G = Gall + wsel * 16384;
    const int O = (wsel == 0 || wsel == 2) ? 128 : 64;
    __shared__ float u[128], t[128], red[4];
    int tid = threadIdx.x;
    if (tid < O) u[tid] = 1.0f / sqrtf((float)O);
    __syncthreads();
    for (int it = 0; it < 3; ++it) {
        if (tid < O) {
            float s = 0.f;
            const float4* gr = reinterpret_cast<const float4*>(G + (size_t)tid * 128);
            for (int j = 0; j < O / 4; ++j) {
                float4 g = gr[j];
                s += g.x * u[4*j] + g.y * u[4*j+1] + g.z * u[4*j+2] + g.w * u[4*j+3];
            }
            t[tid] = s;
        }
        __syncthreads();
        float loc = (tid < O) ? t[tid] * t[tid] : 0.f;
        float nt = sqrtf(block_sum(loc, red));
        if (it == 2) {
            float locd = (tid < O) ? u[tid] * t[tid] : 0.f;
            float dot = block_sum(locd, red);
            if (tid == 0) sig[wsel] = nt / sqrtf(dot + 1e-24f);
        } else {
            if (tid < O) u[tid] = t[tid] / (nt + 1e-12f);
            __syncthreads();
        }
    }
}

// ---------------- conv weight prep: [O][C][3][3]/sigma -> bf16 [O][tap*C+ci] ----------------
__global__ __launch_bounds__(256)
void prep_conv_w(const float* __restrict__ cW1, const float* __restrict__ cW2,
                 const float* __restrict__ fW1, const float* __restrict__ fW2,
                 const float* __restrict__ sig,
                 u16* wc1, u16* wc2, u16* wf1, u16* wf2) {
    int wsel = blockIdx.y;
    const float* src; u16* dst; int O, C;
    switch (wsel) {
        case 0:  src = cW1; dst = wc1; O = 128; C = 64;  break;
        case 1:  src = cW2; dst = wc2; O = 64;  C = 128; break;
        case 2:  src = fW1; dst = wf1; O = 128; C = 128; break;
        default: src = fW2; dst = wf2; O = 64;  C = 128; break;
    }
    int idx = blockIdx.x * 256 + threadIdx.x;
    if (idx >= O * C * 9) return;
    int o = idx / (C * 9);
    int rem = idx - o * (C * 9);
    int ci = rem / 9, tap = rem - ci * 9;
    float v = src[idx] / sig[wsel];
    dst[(size_t)o * (C * 9) + tap * C + ci] = f2bf(v);
}

// ---------------- projection weight/bias prep ----------------
__global__ __launch_bounds__(256)
void prep_proj(const float* q1W, const float* k1W, const float* v1W, const float* s1W,
               const float* q2W, const float* k2W, const float* v2W, const float* s2W,
               const float* q1b, const float* k1b, const float* v1b, const float* s1b,
               const float* q2b, const float* k2b, const float* v2b, const float* s2b,
               u16* wp1, u16* wp2, float* b1, float* b2) {
    const float* W1[4] = {q1W, k1W, v1W, s1W};
    const float* W2[4] = {q2W, k2W, v2W, s2W};
    const float* Bb1[4] = {q1b, k1b, v1b, s1b};
    const float* Bb2[4] = {q2b, k2b, v2b, s2b};
    int idx = blockIdx.x * 256 + threadIdx.x;
    if (idx < 32768) {
        int w = idx >> 13, r = idx & 8191;
        wp1[(size_t)w * 8192 + r] = f2bf(W1[w][r]);
    } else if (idx < 65536) {
        int j = idx - 32768; int w = j >> 13, r = j & 8191;
        wp2[(size_t)w * 8192 + r] = f2bf(W2[w][r]);
    } else if (idx < 66048) {
        int j = idx - 65536; int w = j >> 7; b1[j] = Bb1[w][j & 127];
    } else if (idx < 66304) {
        int j = idx - 66048; int w = j >> 6; b2[j] = Bb2[w][j & 63];
    }
}

// ---------------- x NCHW f32 -> [pix][64] bf16 ----------------
__global__ __launch_bounds__(256)
void convert_x(const float* __restrict__ x, u16* __restrict__ xb) {
    __shared__ float tile[64][65];
    int b = blockIdx.x >> 6, y = blockIdx.x & 63;
    int tid = threadIdx.x;
    #pragma unroll
    for (int i = 0; i < 16; ++i) {
        int c = (tid >> 6) + i * 4;
        tile[c][tid & 63] = x[(((size_t)b * 64 + c) << 12) + (y << 6) + (tid & 63)];
    }
    __syncthreads();
    #pragma unroll
    for (int i = 0; i < 16; ++i) {
        int idx = tid + i * 256;
        int p = idx >> 6, c = idx & 63;
        xb[(((size_t)b << 12) + (y << 6) + p) * 64 + c] = f2bf(tile[c][p]);
    }
}

// ---------------- bf16 MFMA GEMM, implicit im2col, BK=64, ring-2 2-phase ----------------
// BM=64, 4 waves x 32x(BN/2). Ring-2 LDS (48KB @ BN=128 -> 3 blocks/CU resident,
// 32KB @ BN=64 -> grid-bound 4). Guide T3-minimum 2-phase order:
//   stage(kt+1) -> MFMA(kt) -> vmcnt(0) -> barrier
// The drain is cheap: kt+1's loads get the whole MFMA block to land. Raises
// resident MAC work/CU from 1.05M (rd7/rd8) to 1.57M (the measured lever).
// LDS row = 64 k-elems = 128B = 8 chunks; chunk c of row r at slot c^(r&7).
template<int TAPS, int CC, int BN, int OUTM>
__global__ __launch_bounds__(256)
void mm_kernel(const u16* __restrict__ A, const u16* __restrict__ Bw,
               const float* __restrict__ bias, void* __restrict__ Cout,
               int ostride, int ocol0, int do_gelu) {
    constexpr int K = CC * TAPS;
    constexpr int NSTEP = K / 64;
    constexpr int NF = BN / 32;
    constexpr int HN = BN / 2;
    __shared__ u16 Als[2][64 * 64];
    __shared__ u16 Bls[2][BN * 64];
    const int tid = threadIdx.x;
    const int w = tid >> 6;
    const int lane = tid & 63;
    const int m0 = blockIdx.x * 64;
    const int nt0 = blockIdx.y * BN;
    const int wm = w >> 1, wn = w & 1;
    // staging: wave covers 8 rows x 8 chunks; lane -> row +(l>>3)&7, slot l&7;
    // fetch global chunk (l&7)^((l>>3)&7)
    const int cg8 = (((tid & 7) ^ ((tid >> 3) & 7)) << 3);

    const int r0 = (w << 3) + ((tid >> 3) & 7);
    const int mA0 = m0 + r0;
    const int mA1 = mA0 + 32;
    const int yA = (mA0 >> 6) & 63, ibA = mA0 & ~4095;
    const int xA0 = mA0 & 63, xA1 = mA1 & 63;
    const u16* Bbase = Bw + (size_t)(nt0 + r0) * K + cg8;

    // hoisted swizzled ds_read offsets (u16 elems)
    int offA[2][2], offB[2][NF];
    #pragma unroll
    for (int s = 0; s < 2; ++s) {
        #pragma unroll
        for (int mf = 0; mf < 2; ++mf) {
            int R = wm * 32 + mf * 16 + (lane & 15);
            int cl = s * 4 + (lane >> 4);
            offA[s][mf] = R * 64 + ((cl ^ (R & 7)) << 3);
        }
        #pragma unroll
        for (int nf = 0; nf < NF; ++nf) {
            int Rb = wn * HN + nf * 16 + (lane & 15);
            int cl = s * 4 + (lane >> 4);
            offB[s][nf] = Rb * 64 + ((cl ^ (Rb & 7)) << 3);
        }
    }

    f32x4 acc[2][NF];
    #pragma unroll
    for (int i = 0; i < 2; ++i)
        #pragma unroll
        for (int j = 0; j < NF; ++j) {
            f32x4 z = {0.f, 0.f, 0.f, 0.f};
            acc[i][j] = z;
        }

    auto stage = [&](int s) {
        const int buf = s & 1;
        const int kk = s * 64;
        const u16 *ga0, *ga1;
        if constexpr (TAPS == 9) {
            const int tap = kk / CC;
            const int ci0 = kk - tap * CC;
            const int t3 = (tap * 11) >> 5;      // tap/3 for tap<9
            const int dy = t3 - 1, dx = tap - t3 * 3 - 1;
            const int yy = min(max(yA + dy, 0), 63);
            const int xx0 = min(max(xA0 + dx, 0), 63);
            const int xx1 = min(max(xA1 + dx, 0), 63);
            ga0 = A + (size_t)(ibA | (yy << 6) | xx0) * CC + ci0 + cg8;
            ga1 = A + (size_t)(ibA | (yy << 6) | xx1) * CC + ci0 + cg8;
        } else {
            ga0 = A + (size_t)mA0 * CC + kk + cg8;
            ga1 = A + (size_t)mA1 * CC + kk + cg8;
        }
        g2l16(ga0, &Als[buf][(w << 3) * 64]);
        g2l16(ga1, &Als[buf][(32 + (w << 3)) * 64]);
        #pragma unroll
        for (int i = 0; i < BN / 32; ++i)
            g2l16(Bbase + (size_t)i * 32 * K + kk, &Bls[buf][(i * 32 + (w << 3)) * 64]);
    };

    // prologue: tile 0 staged and visible
    stage(0);
    waitvm<0>();
    __builtin_amdgcn_s_barrier();
    __builtin_amdgcn_sched_barrier(0);

    for (int kt = 0; kt < NSTEP; ++kt) {
        if (kt + 1 < NSTEP) stage(kt + 1);     // into buf^1 (safe: prev barrier
                                               // cleared readers of that buf)
        __builtin_amdgcn_sched_barrier(0);
        const u16* Ab = &Als[kt & 1][0];
        const u16* Bb = &Bls[kt & 1][0];
        #pragma unroll
        for (int s = 0; s < 2; ++s) {
            bf16x8 af[2];
            #pragma unroll
            for (int mf = 0; mf < 2; ++mf)
                af[mf] = *reinterpret_cast<const bf16x8*>(Ab + offA[s][mf]);
            #pragma unroll
            for (int nf = 0; nf < NF; ++nf) {
                bf16x8 bfv = *reinterpret_cast<const bf16x8*>(Bb + offB[s][nf]);
                #pragma unroll
                for (int mf = 0; mf < 2; ++mf)
                    acc[mf][nf] = __builtin_amdgcn_mfma_f32_16x16x32_bf16(
                        af[mf], bfv, acc[mf][nf], 0, 0, 0);
            }
        }
        __builtin_amdgcn_sched_barrier(0);
        if (kt + 1 < NSTEP) {
            waitvm<0>();                       // kt+1's loads landed (hidden by MFMA)
            __builtin_amdgcn_s_barrier();      // all waves done reading kt + staging kt+1
            __builtin_amdgcn_sched_barrier(0);
        }
    }

    // epilogue
    #pragma unroll
    for (int mf = 0; mf < 2; ++mf) {
        int mrow = m0 + wm * 32 + mf * 16 + (lane >> 4) * 4;
        #pragma unroll
        for (int nf = 0; nf < NF; ++nf) {
            int col = nt0 + wn * HN + nf * 16 + (lane & 15);
            float bv = bias[col];
            if (OUTM == 0) {
                u16* Co = (u16*)Cout;
                #pragma unroll
                for (int j = 0; j < 4; ++j) {
                    float v = acc[mf][nf][j] + bv;
                    if (do_gelu) v = gelu_f(v);
                    Co[(size_t)(mrow + j) * ostride + ocol0 + col] = f2bf(v);
                }
            } else {
                float* Co = (float*)Cout;
                int b = m0 >> 12;
                int pixb = (mrow & 4095);
                f32x4 vv;
                #pragma unroll
                for (int j = 0; j < 4; ++j)
                    vv[j] = gelu_f(acc[mf][nf][j] + bv);
                *reinterpret_cast<f32x4*>(&Co[((size_t)(b * 64 + col)) * 4096 + pixb]) = vv;
            }
        }
    }
}

// ---------------- attention layer 1: heads=8, d=16, 8ch/lane ----------------
__global__ __launch_bounds__(256)
void attn1_kernel(const u16* __restrict__ qkvs, u16* __restrict__ h) {
    const int tid = threadIdx.x;
    const int l16 = tid & 15;
    const int n = blockIdx.x * 16 + (tid >> 4);
    const int y = (n >> 6) & 63, x = n & 63;
    const u32* qk = (const u32*)qkvs;
    const int nbase = (n << 8) + l16 * 4;

    u32x4 qp = *(const u32x4*)(qk + nbase);
    float q[8];
    #pragma unroll
    for (int i = 0; i < 4; ++i) { q[2*i] = blo(qp[i]); q[2*i+1] = bhi(qp[i]); }

    float al[9];
    float mx = -1e30f;
    #pragma unroll
    for (int e = 0; e < 9; ++e) {
        const int dy = e / 3 - 1, dx = e % 3 - 1;
        const bool valid = (unsigned)(y + dy) < 64u && (unsigned)(x + dx) < 64u;
        const int off = valid ? ((dy * 64 + dx) << 8) : 0;
        u32x4 kp = *(const u32x4*)(qk + nbase + off + 64);
        float p = 0.f;
        #pragma unroll
        for (int i = 0; i < 4; ++i) {
            p = fmaf(q[2*i],   blo(kp[i]), p);
            p = fmaf(q[2*i+1], bhi(kp[i]), p);
        }
        p += __shfl_xor(p, 1);
        al[e] = valid ? p * 0.25f : -1e30f;
        mx = fmaxf(mx, al[e]);
    }
    float s = 0.f;
    #pragma unroll
    for (int e = 0; e < 9; ++e) { al[e] = __expf(al[e] - mx); s += al[e]; }

    float o[8] = {0.f, 0.f, 0.f, 0.f, 0.f, 0.f, 0.f, 0.f};
    #pragma unroll
    for (int e = 0; e < 9; ++e) {
        const int dy = e / 3 - 1, dx = e % 3 - 1;
        const bool valid = (unsigned)(y + dy) < 64u && (unsigned)(x + dx) < 64u;
        const int off = valid ? ((dy * 64 + dx) << 8) : 0;
        u32x4 vp = *(const u32x4*)(qk + nbase + off + 128);
        const float a = al[e];
        #pragma unroll
        for (int i = 0; i < 4; ++i) {
            o[2*i]   = fmaf(a, blo(vp[i]), o[2*i]);
            o[2*i+1] = fmaf(a, bhi(vp[i]), o[2*i+1]);
        }
    }
    const float r = __fdividef(1.0f, s + 1e-16f);
    u32x4 sp = *(const u32x4*)(qk + nbase + 192);
    u32x4 res;
    #pragma unroll
    for (int i = 0; i < 4; ++i) {
        float h0 = gelu_f(fmaf(o[2*i],   r, blo(sp[i])));
        float h1 = gelu_f(fmaf(o[2*i+1], r, bhi(sp[i])));
        res[i] = packbf(h0, h1);
    }
    *(u32x4*)((u32*)h + (n << 6) + l16 * 4) = res;
}

// ---------------- attention layer 2: heads=1, d=64, 8ch/lane ----------------
__global__ __launch_bounds__(256)
void attn2_kernel(const u16* __restrict__ qkvs, u16* __restrict__ xc) {
    const int tid = threadIdx.x;
    const int l8 = tid & 7;
    const int n = blockIdx.x * 32 + (tid >> 3);
    const int y = (n >> 6) & 63, x = n & 63;
    const u32* qk = (const u32*)qkvs;
    const int nbase = (n << 7) + l8 * 4;

    u32x4 qp = *(const u32x4*)(qk + nbase);
    float q[8];
    #pragma unroll
    for (int i = 0; i < 4; ++i) { q[2*i] = blo(qp[i]); q[2*i+1] = bhi(qp[i]); }

    float al[9];
    float mx = -1e30f;
    #pragma unroll
    for (int e = 0; e < 9; ++e) {
        const int dy = e / 3 - 1, dx = e % 3 - 1;
        const bool valid = (unsigned)(y + dy) < 64u && (unsigned)(x + dx) < 64u;
        const int off = valid ? ((dy * 64 + dx) << 7) : 0;
        u32x4 kp = *(const u32x4*)(qk + nbase + off + 32);
        float p = 0.f;
        #pragma unroll
        for (int i = 0; i < 4; ++i) {
            p = fmaf(q[2*i],   blo(kp[i]), p);
            p = fmaf(q[2*i+1], bhi(kp[i]), p);
        }
        p += __shfl_xor(p, 1);
        p += __shfl_xor(p, 2);
        p += __shfl_xor(p, 4);
        al[e] = valid ? p * 0.125f : -1e30f;
        mx = fmaxf(mx, al[e]);
    }
    float s = 0.f;
    #pragma unroll
    for (int e = 0; e < 9; ++e) { al[e] = __expf(al[e] - mx); s += al[e]; }

    float o[8] = {0.f, 0.f, 0.f, 0.f, 0.f, 0.f, 0.f, 0.f};
    #pragma unroll
    for (int e = 0; e < 9; ++e) {
        const int dy = e / 3 - 1, dx = e % 3 - 1;
        const bool valid = (unsigned)(y + dy) < 64u && (unsigned)(x + dx) < 64u;
        const int off = valid ? ((dy * 64 + dx) << 7) : 0;
        u32x4 vp = *(const u32x4*)(qk + nbase + off + 64);
        const float a = al[e];
        #pragma unroll
        for (int i = 0; i < 4; ++i) {
            o[2*i]   = fmaf(a, blo(vp[i]), o[2*i]);
            o[2*i+1] = fmaf(a, bhi(vp[i]), o[2*i+1]);
        }
    }
    const float r = __fdividef(1.0f, s + 1e-16f);
    u32x4 sp = *(const u32x4*)(qk + nbase + 96);
    u32x4 res;
    #pragma unroll
    for (int i = 0; i < 4; ++i) {
        float h0 = gelu_f(fmaf(o[2*i],   r, blo(sp[i])));
        float h1 = gelu_f(fmaf(o[2*i+1], r, bhi(sp[i])));
        res[i] = packbf(h0, h1);
    }
    *(u32x4*)((u32*)xc + (n << 6) + 32 + l8 * 4) = res;
}

// ---------------- host launcher ----------------
extern "C" void kernel_launch(void* const* d_in, const int* in_sizes, int n_in,
                              void* d_out, int out_size, void* d_ws, size_t ws_size,
                              hipStream_t stream) {
    const float* x   = (const float*)d_in[0];
    const float* cW1 = (const float*)d_in[1];
    const float* cb1 = (const float*)d_in[2];
    const float* cW2 = (const float*)d_in[3];
    const float* cb2 = (const float*)d_in[4];
    const float* q1W = (const float*)d_in[5];
    const float* q1b = (const float*)d_in[6];
    const float* k1W = (const float*)d_in[7];
    const float* k1b = (const float*)d_in[8];
    const float* v1W = (const float*)d_in[9];
    const float* v1b = (const float*)d_in[10];
    const float* s1W = (const float*)d_in[11];
    const float* s1b = (const float*)d_in[12];
    const float* q2W = (const float*)d_in[13];
    const float* q2b = (const float*)d_in[14];
    const float* k2W = (const float*)d_in[15];
    const float* k2b = (const float*)d_in[16];
    const float* v2W = (const float*)d_in[17];
    const float* v2b = (const float*)d_in[18];
    const float* s2W = (const float*)d_in[19];
    const float* s2b = (const float*)d_in[20];
    const float* fW1 = (const float*)d_in[21];
    const float* fb1 = (const float*)d_in[22];
    const float* fW2 = (const float*)d_in[23];
    const float* fb2 = (const float*)d_in[24];

    char* ws = (char*)d_ws;
    float* sig  = (float*)(ws + SIG);
    float* b1   = (float*)(ws + B1OFF);
    float* b2   = (float*)(ws + B2OFF);
    u16* wc1    = (u16*)(ws + WC1);
    u16* wc2    = (u16*)(ws + WC2);
    u16* wf1    = (u16*)(ws + WF1);
    u16* wf2    = (u16*)(ws + WF2);
    u16* wp1    = (u16*)(ws + WP1);
    u16* wp2    = (u16*)(ws + WP2);
    u16* xb     = (u16*)(ws + XB);
    u16* hbuf   = (u16*)(ws + HBUF);
    u16* qkvs2  = (u16*)(ws + QKVS2);
    u16* xc     = (u16*)(ws + XC);
    u16* qkvs1  = (u16*)(ws + QKVS1);
    u16* y1     = (u16*)(ws + Y1);
    u16* tbuf   = (u16*)(ws + TBUF);
    float* gram = (float*)(ws + GRAM);
    float* out  = (float*)d_out;

    gram_kernel<<<160, 256, 0, stream>>>(cW1, cW2, fW1, fW2, gram);
    power_kernel<<<4, 256, 0, stream>>>(gram, sig);
    prep_conv_w<<<dim3(576, 4), 256, 0, stream>>>(cW1, cW2, fW1, fW2, sig,
                                                  wc1, wc2, wf1, wf2);
    prep_proj<<<260, 256, 0, stream>>>(q1W, k1W, v1W, s1W, q2W, k2W, v2W, s2W,
                                       q1b, k1b, v1b, s1b, q2b, k2b, v2b, s2b,
                                       wp1, wp2, b1, b2);
    convert_x<<<1024, 256, 0, stream>>>(x, xb);

    // proj1: [N][64] x [512][64]^T -> qkvs1 [N][512]   (1 step)
    mm_kernel<1, 64, 128, 0><<<dim3(1024, 4), 256, 0, stream>>>(
        xb, wp1, b1, qkvs1, 512, 0, 0);
    attn1_kernel<<<NPIX / 16, 256, 0, stream>>>(qkvs1, hbuf);
    // proj2: [N][128] x [256][128]^T -> qkvs2 [N][256]  (2 steps)
    mm_kernel<1, 128, 128, 0><<<dim3(1024, 2), 256, 0, stream>>>(
        hbuf, wp2, b2, qkvs2, 256, 0, 0);
    attn2_kernel<<<NPIX / 32, 256, 0, stream>>>(qkvs2, xc);

    // conv1: im2col(xb, C=64) x [128][576]^T -> y1 [N][128], gelu  (9 steps)
    mm_kernel<9, 64, 128, 0><<<dim3(1024, 1), 256, 0, stream>>>(
        xb, wc1, cb1, y1, 128, 0, 1);
    // conv2: im2col(y1, C=128) x [64][1152]^T -> xc cols 0..63, gelu (18 steps)
    mm_kernel<9, 128, 64, 0><<<dim3(1024, 1), 256, 0, stream>>>(
        y1, wc2, cb2, xc, 128, 0, 1);
    // conv3: im2col(xc, C=128) x [128][1152]^T -> t [N][128], gelu (18 steps)
    mm_kernel<9, 128, 128, 0><<<dim3(1024, 1), 256, 0, stream>>>(
        xc, wf1, fb1, tbuf, 128, 0, 1);
    // conv4: im2col(t, C=128) x [64][1152]^T -> out f32 NCHW, gelu (18 steps)
    mm_kernel<9, 128, 64, 1><<<dim3(1024, 1), 256, 0, stream>>>(
        tbuf, wf2, fb2, out, 0, 0, 1);
}

// Round 12
// 210.022 us; speedup vs baseline: 1.7135x; 1.1080x over previous
//
#include <hip/hip_runtime.h>
#include <hip/hip_bf16.h>

typedef unsigned int  u32;
typedef unsigned short u16;
typedef __attribute__((ext_vector_type(8))) short bf16x8;
typedef __attribute__((ext_vector_type(4))) float f32x4;
typedef __attribute__((ext_vector_type(4))) u32 u32x4;

#define NPIX 65536

// ---------------- ws byte offsets ----------------
constexpr size_t SIG   = 0;
constexpr size_t B1OFF = 256;
constexpr size_t B2OFF = B1OFF + 2048;
constexpr size_t WC1   = B2OFF + 1024;        // 128x576 bf16
constexpr size_t WC2   = WC1 + 147456;        // 64x1152
constexpr size_t WF1   = WC2 + 147456;        // 128x1152
constexpr size_t WF2   = WF1 + 294912;        // 64x1152
constexpr size_t WP1   = WF2 + 147456;        // 512x64
constexpr size_t WP2   = WP1 + 65536;         // 256x128
constexpr size_t XB    = WP2 + 65536;         // 65536x64 bf16
constexpr size_t HBUF  = XB + 8388608;        // 65536x128 bf16
constexpr size_t QKVS2 = HBUF + 16777216;     // 65536x256 bf16
constexpr size_t XC    = QKVS2 + 33554432;    // 65536x128 bf16 concat
constexpr size_t QKVS1 = XC + 16777216;       // 65536x512 bf16
constexpr size_t Y1    = QKVS1;
constexpr size_t TBUF  = QKVS1 + 16777216;
constexpr size_t GRAM  = QKVS1 + 67108864;

// ---------------- helpers ----------------
__device__ __forceinline__ float gelu_f(float v) {
    float xa = fabsf(v) * 0.70710678118654752f;
    float t  = __fdividef(1.0f, fmaf(0.3275911f, xa, 1.0f));
    float poly = t * fmaf(t, fmaf(t, fmaf(t, fmaf(t, 1.061405429f, -1.453152027f),
                   1.421413741f), -0.284496736f), 0.254829592f);
    float erfv = 1.0f - poly * __expf(-xa * xa);
    erfv = copysignf(erfv, v);
    return 0.5f * v * (1.0f + erfv);
}
__device__ __forceinline__ u16 f2bf(float f) {
    __hip_bfloat16 b = __float2bfloat16(f);
    return *reinterpret_cast<u16*>(&b);
}
__device__ __forceinline__ float blo(u32 u) {
    union { u32 i; float f; } x; x.i = u << 16; return x.f;
}
__device__ __forceinline__ float bhi(u32 u) {
    union { u32 i; float f; } x; x.i = u & 0xffff0000u; return x.f;
}
__device__ __forceinline__ u32 packbf(float a, float b) {
    return (u32)f2bf(a) | ((u32)f2bf(b) << 16);
}
__device__ __forceinline__ void g2l16(const void* g, void* l) {
    __builtin_amdgcn_global_load_lds(
        (const __attribute__((address_space(1))) u32*)g,
        (__attribute__((address_space(3))) u32*)l, 16, 0, 0);
}

// ---------------- block reduction ----------------
__device__ float block_sum(float vv, float* red) {
    #pragma unroll
    for (int m = 1; m < 64; m <<= 1) vv += __shfl_xor(vv, m);
    int tid = threadIdx.x;
    __syncthreads();
    if ((tid & 63) == 0) red[tid >> 6] = vv;
    __syncthreads();
    return red[0] + red[1] + red[2] + red[3];
}

// ---------------- Gram matrix ----------------
__global__ __launch_bounds__(256)
void gram_kernel(const float* __restrict__ cW1, const float* __restrict__ cW2,
                 const float* __restrict__ fW1, const float* __restrict__ fW2,
                 float* __restrict__ Gall) {
    int bid = blockIdx.x;
    const float* W; int O, K, wsel, tile;
    if (bid < 64)       { W = cW1; O = 128; K = 576;  wsel = 0; tile = bid; }
    else if (bid < 80)  { W = cW2; O = 64;  K = 1152; wsel = 1; tile = bid - 64; }
    else if (bid < 144) { W = fW1; O = 128; K = 1152; wsel = 2; tile = bid - 80; }
    else                { W = fW2; O = 64;  K = 1152; wsel = 3; tile = bid - 144; }
    int ntiles = O >> 4;
    int ti0 = (tile / ntiles) << 4, tj0 = (tile % ntiles) << 4;
    __shared__ float Wi[16][33], Wj[16][33];
    int tid = threadIdx.x;
    int ti = tid >> 4, tj = tid & 15;
    int r = tid >> 5, c = tid & 31;
    float acc = 0.f;
    for (int k0 = 0; k0 < K; k0 += 32) {
        Wi[r][c]     = W[(size_t)(ti0 + r) * K + k0 + c];
        Wi[r + 8][c] = W[(size_t)(ti0 + r + 8) * K + k0 + c];
        Wj[r][c]     = W[(size_t)(tj0 + r) * K + k0 + c];
        Wj[r + 8][c] = W[(size_t)(tj0 + r + 8) * K + k0 + c];
        __syncthreads();
        #pragma unroll
        for (int k = 0; k < 32; ++k)
            acc += Wi[ti][k] * Wj[tj][k];
        __syncthreads();
    }
    Gall[wsel * 16384 + (ti0 + ti) * 128 + (tj0 + tj)] = acc;
}

// ---------------- power iteration ----------------
__global__ __launch_bounds__(256)
void power_kernel(const float* __restrict__ Gall, float* __restrict__ sig) {
    int wsel = blockIdx.x;
    const float* G = Gall + wsel * 16384;
    const int O = (wsel == 0 || wsel == 2) ? 128 : 64;
    __shared__ float u[128], t[128], red[4];
    int tid = threadIdx.x;
    if (tid < O) u[tid] = 1.0f / sqrtf((float)O);
    __syncthreads();
    for (int it = 0; it < 3; ++it) {
        if (tid < O) {
            float s = 0.f;
            const float4* gr = reinterpret_cast<const float4*>(G + (size_t)tid * 128);
            for (int j = 0; j < O / 4; ++j) {
                float4 g = gr[j];
                s += g.x * u[4*j] + g.y * u[4*j+1] + g.z * u[4*j+2] + g.w * u[4*j+3];
            }
            t[tid] = s;
        }
        __syncthreads();
        float loc = (tid < O) ? t[tid] * t[tid] : 0.f;
        float nt = sqrtf(block_sum(loc, red));
        if (it == 2) {
            float locd = (tid < O) ? u[tid] * t[tid] : 0.f;
            float dot = block_sum(locd, red);
            if (tid == 0) sig[wsel] = nt / sqrtf(dot + 1e-24f);
        } else {
            if (tid < O) u[tid] = t[tid] / (nt + 1e-12f);
            __syncthreads();
        }
    }
}

// ---------------- conv weight prep: [O][C][3][3]/sigma -> bf16 [O][tap*C+ci] ----------------
__global__ __launch_bounds__(256)
void prep_conv_w(const float* __restrict__ cW1, const float* __restrict__ cW2,
                 const float* __restrict__ fW1, const float* __restrict__ fW2,
                 const float* __restrict__ sig,
                 u16* wc1, u16* wc2, u16* wf1, u16* wf2) {
    int wsel = blockIdx.y;
    const float* src; u16* dst; int O, C;
    switch (wsel) {
        case 0:  src = cW1; dst = wc1; O = 128; C = 64;  break;
        case 1:  src = cW2; dst = wc2; O = 64;  C = 128; break;
        case 2:  src = fW1; dst = wf1; O = 128; C = 128; break;
        default: src = fW2; dst = wf2; O = 64;  C = 128; break;
    }
    int idx = blockIdx.x * 256 + threadIdx.x;
    if (idx >= O * C * 9) return;
    int o = idx / (C * 9);
    int rem = idx - o * (C * 9);
    int ci = rem / 9, tap = rem - ci * 9;
    float v = src[idx] / sig[wsel];
    dst[(size_t)o * (C * 9) + tap * C + ci] = f2bf(v);
}

// ---------------- projection weight/bias prep ----------------
__global__ __launch_bounds__(256)
void prep_proj(const float* q1W, const float* k1W, const float* v1W, const float* s1W,
               const float* q2W, const float* k2W, const float* v2W, const float* s2W,
               const float* q1b, const float* k1b, const float* v1b, const float* s1b,
               const float* q2b, const float* k2b, const float* v2b, const float* s2b,
               u16* wp1, u16* wp2, float* b1, float* b2) {
    const float* W1[4] = {q1W, k1W, v1W, s1W};
    const float* W2[4] = {q2W, k2W, v2W, s2W};
    const float* Bb1[4] = {q1b, k1b, v1b, s1b};
    const float* Bb2[4] = {q2b, k2b, v2b, s2b};
    int idx = blockIdx.x * 256 + threadIdx.x;
    if (idx < 32768) {
        int w = idx >> 13, r = idx & 8191;
        wp1[(size_t)w * 8192 + r] = f2bf(W1[w][r]);
    } else if (idx < 65536) {
        int j = idx - 32768; int w = j >> 13, r = j & 8191;
        wp2[(size_t)w * 8192 + r] = f2bf(W2[w][r]);
    } else if (idx < 66048) {
        int j = idx - 65536; int w = j >> 7; b1[j] = Bb1[w][j & 127];
    } else if (idx < 66304) {
        int j = idx - 66048; int w = j >> 6; b2[j] = Bb2[w][j & 63];
    }
}

// ---------------- x NCHW f32 -> [pix][64] bf16 ----------------
__global__ __launch_bounds__(256)
void convert_x(const float* __restrict__ x, u16* __restrict__ xb) {
    __shared__ float tile[64][65];
    int b = blockIdx.x >> 6, y = blockIdx.x & 63;
    int tid = threadIdx.x;
    #pragma unroll
    for (int i = 0; i < 16; ++i) {
        int c = (tid >> 6) + i * 4;
        tile[c][tid & 63] = x[(((size_t)b * 64 + c) << 12) + (y << 6) + (tid & 63)];
    }
    __syncthreads();
    #pragma unroll
    for (int i = 0; i < 16; ++i) {
        int idx = tid + i * 256;
        int p = idx >> 6, c = idx & 63;
        xb[(((size_t)b << 12) + (y << 6) + p) * 64 + c] = f2bf(tile[c][p]);
    }
}

// ---------------- bf16 MFMA GEMM, implicit im2col, BK=CC (one tap/stage) ----------------
// BM=128, 4 waves (2x2), each wave 64 x BN/2. SINGLE-buffered LDS (32-64KB ->
// 2-3 blocks/CU), NSTEP = TAPS (9 for convs, 1 for projs): the measured law is
// time ~ serial-steps x ~1.1us, so minimize steps. Plain __syncthreads() only
// (compiler emits the vmcnt drains; no manual scheduling - m97 regime).
// LDS row = CC elems; 16B chunk c of row r at slot c^(r&(NCH-1)), both-sides.
template<int TAPS, int CC, int BN, int OUTM>
__global__ __launch_bounds__(256)
void mm_kernel(const u16* __restrict__ A, const u16* __restrict__ Bw,
               const float* __restrict__ bias, void* __restrict__ Cout,
               int ostride, int ocol0, int do_gelu) {
    constexpr int K = CC * TAPS;
    constexpr int NSTEP = TAPS;
    constexpr int NCH = CC / 8;           // 16B chunks per row
    constexpr int NKS = CC / 32;          // k-slices per step
    constexpr int NF = BN / 32;
    constexpr int HN = BN / 2;
    constexpr int RSTEP = 256 / NCH;      // rows covered per staging sweep
    constexpr int ALD = 128 / RSTEP;      // A loads / thread / stage
    constexpr int BLD = BN / RSTEP;       // B loads / thread / stage
    __shared__ u16 Als[128 * CC];
    __shared__ u16 Bls[BN * CC];
    const int tid = threadIdx.x;
    const int w = tid >> 6;
    const int lane = tid & 63;
    const int m0 = blockIdx.x * 128;
    const int nt0 = blockIdx.y * BN;
    const int wm = w >> 1, wn = w & 1;

    const int srow = tid / NCH;           // staging row (mod RSTEP)
    const int sslot = tid % NCH;
    const int csrc = ((sslot ^ (srow & (NCH - 1))) << 3);   // elems
    const u16* Bbase = Bw + (size_t)(nt0 + srow) * K + csrc;

    // hoisted swizzled ds_read offsets (u16 elems)
    int offA[NKS][4], offB[NKS][NF];
    #pragma unroll
    for (int ks = 0; ks < NKS; ++ks) {
        #pragma unroll
        for (int mf = 0; mf < 4; ++mf) {
            int R = wm * 64 + mf * 16 + (lane & 15);
            int slot = (ks * 4 + (lane >> 4)) ^ (R & (NCH - 1));
            offA[ks][mf] = R * CC + slot * 8;
        }
        #pragma unroll
        for (int nf = 0; nf < NF; ++nf) {
            int Rb = wn * HN + nf * 16 + (lane & 15);
            int slot = (ks * 4 + (lane >> 4)) ^ (Rb & (NCH - 1));
            offB[ks][nf] = Rb * CC + slot * 8;
        }
    }

    f32x4 acc[4][NF];
    #pragma unroll
    for (int i = 0; i < 4; ++i)
        #pragma unroll
        for (int j = 0; j < NF; ++j) {
            f32x4 z = {0.f, 0.f, 0.f, 0.f};
            acc[i][j] = z;
        }

    #pragma unroll
    for (int kt = 0; kt < NSTEP; ++kt) {
        const int kk = kt * CC;
        const int dy = (TAPS == 9) ? (kt / 3 - 1) : 0;
        const int dx = (TAPS == 9) ? (kt % 3 - 1) : 0;
        // ---- stage tap kt (A) ----
        #pragma unroll
        for (int i = 0; i < ALD; ++i) {
            const int m = m0 + srow + i * RSTEP;
            const u16* ga;
            if constexpr (TAPS == 9) {
                int yy = ((m >> 6) & 63) + dy; yy = min(max(yy, 0), 63);
                int xx = (m & 63) + dx;        xx = min(max(xx, 0), 63);
                ga = A + (size_t)((m & ~4095) | (yy << 6) | xx) * CC + csrc;
            } else {
                ga = A + (size_t)m * CC + csrc;
            }
            g2l16(ga, &Als[(srow + i * RSTEP) * CC + sslot * 8]);
        }
        // ---- stage tap kt (B) ----
        #pragma unroll
        for (int i = 0; i < BLD; ++i)
            g2l16(Bbase + (size_t)i * RSTEP * K + kk,
                  &Bls[(srow + i * RSTEP) * CC + sslot * 8]);

        __syncthreads();                  // implicit vmcnt(0): tile visible

        #pragma unroll
        for (int ks = 0; ks < NKS; ++ks) {
            bf16x8 af[4];
            #pragma unroll
            for (int mf = 0; mf < 4; ++mf)
                af[mf] = *reinterpret_cast<const bf16x8*>(&Als[offA[ks][mf]]);
            #pragma unroll
            for (int nf = 0; nf < NF; ++nf) {
                bf16x8 bfv = *reinterpret_cast<const bf16x8*>(&Bls[offB[ks][nf]]);
                #pragma unroll
                for (int mf = 0; mf < 4; ++mf)
                    acc[mf][nf] = __builtin_amdgcn_mfma_f32_16x16x32_bf16(
                        af[mf], bfv, acc[mf][nf], 0, 0, 0);
            }
        }
        if (kt + 1 < NSTEP) __syncthreads();   // readers done before overwrite
    }

    // epilogue
    #pragma unroll
    for (int mf = 0; mf < 4; ++mf) {
        int mrow = m0 + wm * 64 + mf * 16 + (lane >> 4) * 4;
        #pragma unroll
        for (int nf = 0; nf < NF; ++nf) {
            int col = nt0 + wn * HN + nf * 16 + (lane & 15);
            float bv = bias[col];
            if (OUTM == 0) {
                u16* Co = (u16*)Cout;
                #pragma unroll
                for (int j = 0; j < 4; ++j) {
                    float v = acc[mf][nf][j] + bv;
                    if (do_gelu) v = gelu_f(v);
                    Co[(size_t)(mrow + j) * ostride + ocol0 + col] = f2bf(v);
                }
            } else {
                float* Co = (float*)Cout;
                int b = m0 >> 12;
                int pixb = (mrow & 4095);
                f32x4 vv;
                #pragma unroll
                for (int j = 0; j < 4; ++j)
                    vv[j] = gelu_f(acc[mf][nf][j] + bv);
                *reinterpret_cast<f32x4*>(&Co[((size_t)(b * 64 + col)) * 4096 + pixb]) = vv;
            }
        }
    }
}

// ---------------- attention layer 1: heads=8, d=16, 8ch/lane ----------------
__global__ __launch_bounds__(256)
void attn1_kernel(const u16* __restrict__ qkvs, u16* __restrict__ h) {
    const int tid = threadIdx.x;
    const int l16 = tid & 15;
    const int n = blockIdx.x * 16 + (tid >> 4);
    const int y = (n >> 6) & 63, x = n & 63;
    const u32* qk = (const u32*)qkvs;
    const int nbase = (n << 8) + l16 * 4;

    u32x4 qp = *(const u32x4*)(qk + nbase);
    float q[8];
    #pragma unroll
    for (int i = 0; i < 4; ++i) { q[2*i] = blo(qp[i]); q[2*i+1] = bhi(qp[i]); }

    float al[9];
    float mx = -1e30f;
    #pragma unroll
    for (int e = 0; e < 9; ++e) {
        const int dy = e / 3 - 1, dx = e % 3 - 1;
        const bool valid = (unsigned)(y + dy) < 64u && (unsigned)(x + dx) < 64u;
        const int off = valid ? ((dy * 64 + dx) << 8) : 0;
        u32x4 kp = *(const u32x4*)(qk + nbase + off + 64);
        float p = 0.f;
        #pragma unroll
        for (int i = 0; i < 4; ++i) {
            p = fmaf(q[2*i],   blo(kp[i]), p);
            p = fmaf(q[2*i+1], bhi(kp[i]), p);
        }
        p += __shfl_xor(p, 1);
        al[e] = valid ? p * 0.25f : -1e30f;
        mx = fmaxf(mx, al[e]);
    }
    float s = 0.f;
    #pragma unroll
    for (int e = 0; e < 9; ++e) { al[e] = __expf(al[e] - mx); s += al[e]; }

    float o[8] = {0.f, 0.f, 0.f, 0.f, 0.f, 0.f, 0.f, 0.f};
    #pragma unroll
    for (int e = 0; e < 9; ++e) {
        const int dy = e / 3 - 1, dx = e % 3 - 1;
        const bool valid = (unsigned)(y + dy) < 64u && (unsigned)(x + dx) < 64u;
        const int off = valid ? ((dy * 64 + dx) << 8) : 0;
        u32x4 vp = *(const u32x4*)(qk + nbase + off + 128);
        const float a = al[e];
        #pragma unroll
        for (int i = 0; i < 4; ++i) {
            o[2*i]   = fmaf(a, blo(vp[i]), o[2*i]);
            o[2*i+1] = fmaf(a, bhi(vp[i]), o[2*i+1]);
        }
    }
    const float r = __fdividef(1.0f, s + 1e-16f);
    u32x4 sp = *(const u32x4*)(qk + nbase + 192);
    u32x4 res;
    #pragma unroll
    for (int i = 0; i < 4; ++i) {
        float h0 = gelu_f(fmaf(o[2*i],   r, blo(sp[i])));
        float h1 = gelu_f(fmaf(o[2*i+1], r, bhi(sp[i])));
        res[i] = packbf(h0, h1);
    }
    *(u32x4*)((u32*)h + (n << 6) + l16 * 4) = res;
}

// ---------------- attention layer 2: heads=1, d=64, 8ch/lane ----------------
__global__ __launch_bounds__(256)
void attn2_kernel(const u16* __restrict__ qkvs, u16* __restrict__ xc) {
    const int tid = threadIdx.x;
    const int l8 = tid & 7;
    const int n = blockIdx.x * 32 + (tid >> 3);
    const int y = (n >> 6) & 63, x = n & 63;
    const u32* qk = (const u32*)qkvs;
    const int nbase = (n << 7) + l8 * 4;

    u32x4 qp = *(const u32x4*)(qk + nbase);
    float q[8];
    #pragma unroll
    for (int i = 0; i < 4; ++i) { q[2*i] = blo(qp[i]); q[2*i+1] = bhi(qp[i]); }

    float al[9];
    float mx = -1e30f;
    #pragma unroll
    for (int e = 0; e < 9; ++e) {
        const int dy = e / 3 - 1, dx = e % 3 - 1;
        const bool valid = (unsigned)(y + dy) < 64u && (unsigned)(x + dx) < 64u;
        const int off = valid ? ((dy * 64 + dx) << 7) : 0;
        u32x4 kp = *(const u32x4*)(qk + nbase + off + 32);
        float p = 0.f;
        #pragma unroll
        for (int i = 0; i < 4; ++i) {
            p = fmaf(q[2*i],   blo(kp[i]), p);
            p = fmaf(q[2*i+1], bhi(kp[i]), p);
        }
        p += __shfl_xor(p, 1);
        p += __shfl_xor(p, 2);
        p += __shfl_xor(p, 4);
        al[e] = valid ? p * 0.125f : -1e30f;
        mx = fmaxf(mx, al[e]);
    }
    float s = 0.f;
    #pragma unroll
    for (int e = 0; e < 9; ++e) { al[e] = __expf(al[e] - mx); s += al[e]; }

    float o[8] = {0.f, 0.f, 0.f, 0.f, 0.f, 0.f, 0.f, 0.f};
    #pragma unroll
    for (int e = 0; e < 9; ++e) {
        const int dy = e / 3 - 1, dx = e % 3 - 1;
        const bool valid = (unsigned)(y + dy) < 64u && (unsigned)(x + dx) < 64u;
        const int off = valid ? ((dy * 64 + dx) << 7) : 0;
        u32x4 vp = *(const u32x4*)(qk + nbase + off + 64);
        const float a = al[e];
        #pragma unroll
        for (int i = 0; i < 4; ++i) {
            o[2*i]   = fmaf(a, blo(vp[i]), o[2*i]);
            o[2*i+1] = fmaf(a, bhi(vp[i]), o[2*i+1]);
        }
    }
    const float r = __fdividef(1.0f, s + 1e-16f);
    u32x4 sp = *(const u32x4*)(qk + nbase + 96);
    u32x4 res;
    #pragma unroll
    for (int i = 0; i < 4; ++i) {
        float h0 = gelu_f(fmaf(o[2*i],   r, blo(sp[i])));
        float h1 = gelu_f(fmaf(o[2*i+1], r, bhi(sp[i])));
        res[i] = packbf(h0, h1);
    }
    *(u32x4*)((u32*)xc + (n << 6) + 32 + l8 * 4) = res;
}

// ---------------- host launcher ----------------
extern "C" void kernel_launch(void* const* d_in, const int* in_sizes, int n_in,
                              void* d_out, int out_size, void* d_ws, size_t ws_size,
                              hipStream_t stream) {
    const float* x   = (const float*)d_in[0];
    const float* cW1 = (const float*)d_in[1];
    const float* cb1 = (const float*)d_in[2];
    const float* cW2 = (const float*)d_in[3];
    const float* cb2 = (const float*)d_in[4];
    const float* q1W = (const float*)d_in[5];
    const float* q1b = (const float*)d_in[6];
    const float* k1W = (const float*)d_in[7];
    const float* k1b = (const float*)d_in[8];
    const float* v1W = (const float*)d_in[9];
    const float* v1b = (const float*)d_in[10];
    const float* s1W = (const float*)d_in[11];
    const float* s1b = (const float*)d_in[12];
    const float* q2W = (const float*)d_in[13];
    const float* q2b = (const float*)d_in[14];
    const float* k2W = (const float*)d_in[15];
    const float* k2b = (const float*)d_in[16];
    const float* v2W = (const float*)d_in[17];
    const float* v2b = (const float*)d_in[18];
    const float* s2W = (const float*)d_in[19];
    const float* s2b = (const float*)d_in[20];
    const float* fW1 = (const float*)d_in[21];
    const float* fb1 = (const float*)d_in[22];
    const float* fW2 = (const float*)d_in[23];
    const float* fb2 = (const float*)d_in[24];

    char* ws = (char*)d_ws;
    float* sig  = (float*)(ws + SIG);
    float* b1   = (float*)(ws + B1OFF);
    float* b2   = (float*)(ws + B2OFF);
    u16* wc1    = (u16*)(ws + WC1);
    u16* wc2    = (u16*)(ws + WC2);
    u16* wf1    = (u16*)(ws + WF1);
    u16* wf2    = (u16*)(ws + WF2);
    u16* wp1    = (u16*)(ws + WP1);
    u16* wp2    = (u16*)(ws + WP2);
    u16* xb     = (u16*)(ws + XB);
    u16* hbuf   = (u16*)(ws + HBUF);
    u16* qkvs2  = (u16*)(ws + QKVS2);
    u16* xc     = (u16*)(ws + XC);
    u16* qkvs1  = (u16*)(ws + QKVS1);
    u16* y1     = (u16*)(ws + Y1);
    u16* tbuf   = (u16*)(ws + TBUF);
    float* gram = (float*)(ws + GRAM);
    float* out  = (float*)d_out;

    gram_kernel<<<160, 256, 0, stream>>>(cW1, cW2, fW1, fW2, gram);
    power_kernel<<<4, 256, 0, stream>>>(gram, sig);
    prep_conv_w<<<dim3(576, 4), 256, 0, stream>>>(cW1, cW2, fW1, fW2, sig,
                                                  wc1, wc2, wf1, wf2);
    prep_proj<<<260, 256, 0, stream>>>(q1W, k1W, v1W, s1W, q2W, k2W, v2W, s2W,
                                       q1b, k1b, v1b, s1b, q2b, k2b, v2b, s2b,
                                       wp1, wp2, b1, b2);
    convert_x<<<1024, 256, 0, stream>>>(x, xb);

    // proj1: [N][64] x [512][64]^T -> qkvs1 [N][512]   (1 step)
    mm_kernel<1, 64, 128, 0><<<dim3(512, 4), 256, 0, stream>>>(
        xb, wp1, b1, qkvs1, 512, 0, 0);
    attn1_kernel<<<NPIX / 16, 256, 0, stream>>>(qkvs1, hbuf);
    // proj2: [N][128] x [256][128]^T -> qkvs2 [N][256]  (1 step)
    mm_kernel<1, 128, 128, 0><<<dim3(512, 2), 256, 0, stream>>>(
        hbuf, wp2, b2, qkvs2, 256, 0, 0);
    attn2_kernel<<<NPIX / 32, 256, 0, stream>>>(qkvs2, xc);

    // conv1: im2col(xb, C=64) x [128][576]^T -> y1 [N][128], gelu  (9 steps)
    mm_kernel<9, 64, 128, 0><<<dim3(512, 1), 256, 0, stream>>>(
        xb, wc1, cb1, y1, 128, 0, 1);
    // conv2: im2col(y1, C=128) x [64][1152]^T -> xc cols 0..63, gelu (9 steps)
    mm_kernel<9, 128, 64, 0><<<dim3(512, 1), 256, 0, stream>>>(
        y1, wc2, cb2, xc, 128, 0, 1);
    // conv3: im2col(xc, C=128) x [128][1152]^T -> t [N][128], gelu (9 steps)
    mm_kernel<9, 128, 128, 0><<<dim3(512, 1), 256, 0, stream>>>(
        xc, wf1, fb1, tbuf, 128, 0, 1);
    // conv4: im2col(t, C=128) x [64][1152]^T -> out f32 NCHW, gelu (9 steps)
    mm_kernel<9, 128, 64, 1><<<dim3(512, 1), 256, 0, stream>>>(
        tbuf, wf2, fb2, out, 0, 0, 1);
}